// Round 10
// baseline (163.616 us; speedup 1.0000x reference)
//
#include <hip/hip_runtime.h>
#include <hip/hip_bf16.h>
#include <cstdint>
#include <cstddef>

typedef unsigned short u16;
using frag_ab = __attribute__((ext_vector_type(8))) short;   // 8 bf16 (4 VGPRs)
using f32x4   = __attribute__((ext_vector_type(4))) float;   // 4 fp32 acc

__device__ __forceinline__ u16 f2bf(float x) {
    __hip_bfloat16 h = __float2bfloat16(x);   // RNE
    return *reinterpret_cast<u16*>(&h);
}

// async global->LDS, 16B per lane; LDS dest = wave-uniform base + lane*16 (linear)
__device__ __forceinline__ void gload_lds16(const u16* g, u16* l) {
    __builtin_amdgcn_global_load_lds(
        (const __attribute__((address_space(1))) uint32_t*)g,
        (__attribute__((address_space(3)))       uint32_t*)l,
        16, 0, 0);
}

#define WAITV4() do { asm volatile("s_waitcnt vmcnt(4)" ::: "memory"); \
                      __builtin_amdgcn_sched_barrier(0); } while (0)
#define WAITV0() do { asm volatile("s_waitcnt vmcnt(0)" ::: "memory"); \
                      __builtin_amdgcn_sched_barrier(0); } while (0)
#define BAR()    do { asm volatile("" ::: "memory"); __builtin_amdgcn_s_barrier(); \
                      __builtin_amdgcn_sched_barrier(0); } while (0)
#define LGKMC(N) do { asm volatile("s_waitcnt lgkmcnt(" #N ")" ::: "memory"); \
                      __builtin_amdgcn_sched_barrier(0); } while (0)
#define LGKM0()  LGKMC(0)

// ===========================================================================
// KERNEL gemm3a: 256xBN_ NT bf16 GEMM, TRIPLE-BUFFERED A + double-buffered B,
// 512 thr / 8 waves (4Mx2N).
// R9-proven SINGLE-BARRIER K-TILE: 1 s_barrier + 1 vmcnt(4) + 2 lgkm waits
// per tile. Hazard proof: every wave's frag reads of buffers {ab, bb}
// complete (own LGKM0) BEFORE its BAR; all writes to those buffers (STB@t+1,
// STA@t+1) issue AFTER that same BAR. vmcnt ledger: 12 outstanding at WAITV4
// -> drains A(t+1)+B(t+1), leaves A(t+2).
// L2-footprint-aware XCD tile map (R7-proven): 256-block grids (8,32),
// z folded into gy; XCD c: z=c%nz, compact 4-m-panel slab.
// EPI: 0 = bf16 + bias, plane routed col>>10 (Q/K planes at stride sC)
//      1 = E = exp(s*alpha) bf16 + per-(row,128col-chunk) partial sums
//      2 = bf16 scaled by 1/rowsum(partials) computed in-kernel
//      3 = f32 + bias + residual
//      4 = V-projection: bf16 + bias written TRANSPOSED to vt[b][d][s]
//          via LDS [128][264] tile (replaces the old gemm128_v kernel)
// ===========================================================================
template<int EPI, int BN_>
__global__ __launch_bounds__(512, 2)
void gemm3a(const u16* __restrict__ A, const u16* __restrict__ Bt,
            void* __restrict__ C0,
            const float* __restrict__ b0, const float* __restrict__ resid,
            int K, int lda, int ldb, int ldc,
            long long sA, long long sB, long long sC, float alpha,
            float* __restrict__ partials, int nz)
{
    constexpr int NFQ  = BN_ / 64;            // 16-col frags per NQ quadrant
    constexpr int WN   = BN_ / 2;             // per-wave N
    constexpr int BBUF = BN_ * 64;            // u16 per B buffer
    // A: 3 x 16384 u16 at 0; B: 2 x BBUF u16 at 49152.
    __shared__ __align__(16) u16 lds[49152 + 2 * BBUF];

    // --- L2-footprint-aware XCD tile map (256 blocks exactly) ---
    const int gx  = gridDim.x;                       // n-panels (8)
    const int gid = blockIdx.x + gx * blockIdx.y;    // 0..255
    const int c   = gid & 7;                         // XCD (hw: linear%8)
    const int idx = gid >> 3;                        // 0..31 within XCD
    const int z   = c % nz;
    const int sub = c / nz;                          // 0 .. 8/nz-1
    const int W   = gridDim.y >> 3;                  // m-panels per XCD slab (4)
    const int mp  = sub * W + idx % W;               // m-panel
    const int np  = idx / W;                         // n-panel (0..7)
    const int m0  = mp * 256;
    const int n0  = np * BN_;

    A  += (long long)z * sA;
    Bt += (long long)z * sB;

    const int t    = threadIdx.x;
    const int lane = t & 63;
    const int wave = t >> 6;
    const int wm   = wave >> 1;       // 0..3  (64 rows each)
    const int wn   = wave & 1;        // 0..1  (WN cols each)

    const int r0  = t >> 3;
    const int ssw = (t & 7) ^ (r0 & 7);
    const u16* gsA_0 = A  + (size_t)(m0 +       r0) * lda + ssw * 8;
    const u16* gsA_1 = A  + (size_t)(m0 +  64 + r0) * lda + ssw * 8;
    const u16* gsA_2 = A  + (size_t)(m0 + 128 + r0) * lda + ssw * 8;
    const u16* gsA_3 = A  + (size_t)(m0 + 192 + r0) * lda + ssw * 8;
    const u16* gsB_0 = Bt + (size_t)(n0 +       r0) * ldb + ssw * 8;
    const u16* gsB_1 = Bt + (size_t)(n0 +  64 + r0) * ldb + ssw * 8;
    const u16* gsB_2 = (BN_ == 256) ? Bt + (size_t)(n0 + 128 + r0) * ldb + ssw * 8 : gsB_0;
    const u16* gsB_3 = (BN_ == 256) ? Bt + (size_t)(n0 + 192 + r0) * ldb + ssw * 8 : gsB_1;

#define STA(BUF, H, KT) do {                                                   \
    gload_lds16(((H) ? gsA_2 : gsA_0) + (size_t)(KT) * 64,                     \
                lds + (BUF) * 16384 + (H) * 8192 + t * 8);                     \
    gload_lds16(((H) ? gsA_3 : gsA_1) + (size_t)(KT) * 64,                     \
                lds + (BUF) * 16384 + (H) * 8192 + 4096 + t * 8);              \
} while (0)
#define STB(BUF, H, KT) do {                                                   \
    gload_lds16(((H) ? gsB_2 : gsB_0) + (size_t)(KT) * 64,                     \
                lds + 49152 + (BUF) * BBUF + (H) * 8192 + t * 8);              \
    gload_lds16(((H) ? gsB_3 : gsB_1) + (size_t)(KT) * 64,                     \
                lds + 49152 + (BUF) * BBUF + (H) * 8192 + 4096 + t * 8);       \
} while (0)

    const int ar   = lane & 15;
    const int ko   = lane >> 4;
    const int aoff = (wm * 64 + ar) * 64;
    const int boff = 49152 + (wn * WN + ar) * 64;   // includes B-region base
    const int as0  = ((0 + ko) ^ (ar & 7)) * 8;
    const int as1  = ((4 + ko) ^ (ar & 7)) * 8;

    frag_ab aregA[2][2];              // MQ0 fragments (fixed role)
    frag_ab aregB[2][2];              // MQ1 fragments (fixed role)
    frag_ab breg[2][NFQ][2];          // NQ0 / NQ1, persistent per tile
    f32x4   acc[4][2 * NFQ] = {};

#define RDA3(DST, AB, MQ) do { _Pragma("unroll") for (int mf = 0; mf < 2; ++mf) { \
    DST[mf][0] = *(const frag_ab*)(lds + (AB) + aoff + ((MQ)*2+mf)*1024 + as0); \
    DST[mf][1] = *(const frag_ab*)(lds + (AB) + aoff + ((MQ)*2+mf)*1024 + as1); } } while (0)

#define RDB3(BO, NQ) do { _Pragma("unroll") for (int jf = 0; jf < NFQ; ++jf) { \
    breg[NQ][jf][0] = *(const frag_ab*)(lds + (BO) + boff + ((NQ)*NFQ+jf)*1024 + as0); \
    breg[NQ][jf][1] = *(const frag_ab*)(lds + (BO) + boff + ((NQ)*NFQ+jf)*1024 + as1); } } while (0)

#define MMAQ3(ASET, MQ, NQ) do { __builtin_amdgcn_s_setprio(1);                \
    _Pragma("unroll") for (int mf = 0; mf < 2; ++mf)                           \
    _Pragma("unroll") for (int jf = 0; jf < NFQ; ++jf) {                       \
        acc[(MQ)*2+mf][(NQ)*NFQ+jf] = __builtin_amdgcn_mfma_f32_16x16x32_bf16( \
            ASET[mf][0], breg[NQ][jf][0], acc[(MQ)*2+mf][(NQ)*NFQ+jf], 0,0,0); \
        acc[(MQ)*2+mf][(NQ)*NFQ+jf] = __builtin_amdgcn_mfma_f32_16x16x32_bf16( \
            ASET[mf][1], breg[NQ][jf][1], acc[(MQ)*2+mf][(NQ)*NFQ+jf], 0,0,0); \
    } __builtin_amdgcn_s_setprio(0); } while (0)

    const int nk = K / 64;
    // prologue: A(0), B(0), A(1); WAITV4 drains A(0)+B(0), leaves A(1) flying
    STA(0, 0, 0); STA(0, 1, 0);
    STB(0, 0, 0);
    if constexpr (BN_ == 256) STB(0, 1, 0);
    STA(1, 0, 1); STA(1, 1, 1);
    WAITV4();
    BAR();
    // tile0 MQ0 frags (completion covered by first tile's LGKMC)
    RDA3(aregA, 0, 0);

    int ab = 0, bb = 0;
    for (int tt = 0; tt < nk; ++tt) {
        const int abn = (ab + 1 >= 3) ? 0 : ab + 1;        // (ab+1)%3
        const int ab2 = (ab + 2 >= 3) ? ab - 1 : ab + 2;   // (ab+2)%3
        const int bb1 = bb ^ 1;
        const int tB  = (tt + 1 < nk) ? tt + 1 : nk - 1;   // clamped: benign
        const int tA  = (tt + 2 < nk) ? tt + 2 : nk - 1;   // clamped: benign
        const int AB  = ab * 16384, BB = bb * BBUF;
        const int ABn = abn * 16384;
        // --- single-phase tile: reads + B-stage, 2 MFMA quads, A-stage,
        //     drain, ONE barrier, prefetch, 2 MFMA quads ---
        RDA3(aregB, AB, 1);
        RDB3(BB, 0);
        RDB3(BB, 1);                   // breg1 last-issued: LGKMC leaves it
        STB(bb1, 0, tB);
        if constexpr (BN_ == 256) STB(bb1, 1, tB);
        if constexpr (BN_ == 256) { LGKMC(8); } else { LGKMC(4); }
        MMAQ3(aregA, 0, 0);
        LGKM0();
        MMAQ3(aregA, 0, 1);
        STA(ab2, 0, tA);
        STA(ab2, 1, tA);
        MMAQ3(aregB, 1, 0);            // overlaps the WAITV4 drain below
        WAITV4();
        BAR();
        RDA3(aregA, ABn, 0);           // next tile MQ0 (A(t+1) proven in LDS)
        MMAQ3(aregB, 1, 1);
        ab = abn;
        bb = bb1;
    }

    const int cr = (lane >> 4) * 4;
    const int cc = lane & 15;

    if constexpr (EPI == 4) {
        // ---- V: write transposed to vt[b][d][s] via LDS [128][264] ----
        WAITV0();   // drain pending prefetch gload_lds before reusing LDS
        BAR();
        constexpr int TP = 264;          // u16 row stride (528B; 16B-aligned)
        u16* T = lds;                    // 128*264*2B = 67.6 KB < LDS
        #pragma unroll
        for (int mi = 0; mi < 4; ++mi) {
            const int rloc = wm * 64 + mi * 16 + cr;   // 0..255, mult of 4
            #pragma unroll
            for (int gj = 0; gj < 2 * NFQ; ++gj) {
                const int cl = wn * WN + gj * 16 + cc; // 0..127
                const float bvv = b0[n0 + cl];
                union { u16 u[4]; uint2 q; } pk;
                #pragma unroll
                for (int r = 0; r < 4; ++r) pk.u[r] = f2bf(acc[mi][gj][r] + bvv);
                *(uint2*)&T[cl * TP + rloc] = pk.q;    // 8B-aligned
            }
        }
        BAR();
        const int bb2 = m0 >> 11;        // batch
        const int s0  = m0 & 2047;       // seq offset within batch
        const int d   = t >> 2;          // 0..127 local feature row
        const int q   = t & 3;           // 64-u16 quarter of the 256-row span
        const u16* src = T + d * TP + q * 64;
        u16* dg = (u16*)C0 + (size_t)bb2 * 1024 * 2048
                + (size_t)(n0 + d) * 2048 + s0 + q * 64;
        #pragma unroll
        for (int j = 0; j < 8; ++j)
            ((uint4*)dg)[j] = ((const uint4*)src)[j];
        return;
    }

    // EPI2: fold invl in-kernel. Drain prefetches, reuse LDS for 256 floats.
    float* fl = (float*)lds;
    if constexpr (EPI == 2) {
        WAITV0();
        BAR();
        if (t < 256) {
            const float* p = partials + ((size_t)z * 2048 + m0 + t) * 16;
            float s = 0.0f;
            #pragma unroll
            for (int i = 0; i < 16; ++i) s += p[i];
            fl[t] = 1.0f / s;
        }
        BAR();
    }

    float rs[4][4];
    if constexpr (EPI == 1) {
        #pragma unroll
        for (int mi = 0; mi < 4; ++mi)
            #pragma unroll
            for (int r = 0; r < 4; ++r) rs[mi][r] = 0.0f;
    }

    #pragma unroll
    for (int mi = 0; mi < 4; ++mi) {
        const int rowb = m0 + wm * 64 + mi * 16 + cr;
        const int rloc = wm * 64 + mi * 16 + cr;
        #pragma unroll
        for (int gj = 0; gj < 2 * NFQ; ++gj) {
            const int col = n0 + wn * WN + gj * 16 + cc;
            if constexpr (EPI == 0) {
                // plane-routed bf16 + bias (Q / K planes at stride sC)
                const int plane = col >> 10;
                const int cl    = col & 1023;
                const float bvv = ((plane == 0) ? b0 : resid)[cl];
                u16* Cw = (u16*)C0 + (size_t)plane * sC;
                #pragma unroll
                for (int r = 0; r < 4; ++r)
                    Cw[(size_t)(rowb + r) * ldc + cl] = f2bf(acc[mi][gj][r] + bvv);
            } else {
                const float bvv = (EPI == 3) ? b0[col] : 0.0f;
                #pragma unroll
                for (int r = 0; r < 4; ++r) {
                    const size_t row = (size_t)(rowb + r);
                    float v = acc[mi][gj][r];
                    if (EPI == 1) { v = __expf(v * alpha); rs[mi][r] += v; }
                    if (EPI == 2) v *= fl[rloc + r];
                    v += bvv;
                    if (EPI == 3) {
                        v += resid[row * ldc + col];
                        ((float*)C0)[(size_t)z * sC + row * ldc + col] = v;
                    } else {
                        ((u16*)C0)[(size_t)z * sC + row * ldc + col] = f2bf(v);
                    }
                }
            }
        }
    }

    if constexpr (EPI == 1) {
        #pragma unroll
        for (int mi = 0; mi < 4; ++mi)
            #pragma unroll
            for (int r = 0; r < 4; ++r) {
                float s = rs[mi][r];
                s += __shfl_xor(s, 1); s += __shfl_xor(s, 2);
                s += __shfl_xor(s, 4); s += __shfl_xor(s, 8);
                rs[mi][r] = s;
            }
        if (cc == 0) {
            const int chunk = (n0 >> 7) + wn;   // 128-col chunks (BN256), 16/row
            #pragma unroll
            for (int mi = 0; mi < 4; ++mi) {
                const int rowb = m0 + wm * 64 + mi * 16 + cr;
                #pragma unroll
                for (int r = 0; r < 4; ++r)
                    partials[((size_t)z * 2048 + rowb + r) * 16 + chunk] = rs[mi][r];
            }
        }
    }
#undef STA
#undef STB
#undef RDA3
#undef RDB3
#undef MMAQ3
}

// ---------------------------------------------------------------------------
// Fused prep: blocks [0, NG)   : x = bf16(gelu_exact(tokens)), 8 f32/thread
//             blocks [NG, NG+4096): WT[z][n][k] = bf16(W_z[k][n]), 32x32 tiles
//             (packed uint stores)
// ---------------------------------------------------------------------------
__global__ __launch_bounds__(256)
void prep_kernel(const float4* __restrict__ in, uint4* __restrict__ outp,
                 const float* __restrict__ W0, const float* __restrict__ W1,
                 const float* __restrict__ W2, const float* __restrict__ W3,
                 u16* __restrict__ WT, int D, int NG)
{
    __shared__ float tile[32][33];
    const int b = blockIdx.x;
    const int t = threadIdx.x;
    if (b < NG) {
        const int i = (b * 256 + t) * 2;          // float4 index, 2 consecutive
        float4 x0 = in[i], x1 = in[i + 1];
        auto g = [](float v) { return 0.5f * v * (1.0f + erff(v * 0.70710678118654752f)); };
        union { u16 u[8]; uint4 q; } pk;
        pk.u[0] = f2bf(g(x0.x)); pk.u[1] = f2bf(g(x0.y));
        pk.u[2] = f2bf(g(x0.z)); pk.u[3] = f2bf(g(x0.w));
        pk.u[4] = f2bf(g(x1.x)); pk.u[5] = f2bf(g(x1.y));
        pk.u[6] = f2bf(g(x1.z)); pk.u[7] = f2bf(g(x1.w));
        outp[b * 256 + t] = pk.q;
        return;
    }
    const int j   = b - NG;                 // 0..4095
    const int z   = j >> 10;
    const int rem = j & 1023;
    const int n0  = (rem & 31) * 32;
    const int k0  = (rem >> 5) * 32;
    const float* W = (z == 0) ? W0 : (z == 1) ? W1 : (z == 2) ? W2 : W3;
    u16* o = WT + (size_t)z * D * D;
    const int tx = t & 31, ty = t >> 5;     // 32 x 8 load layout
    #pragma unroll
    for (int r = 0; r < 4; ++r)
        tile[ty + 8 * r][tx] = W[(size_t)(k0 + ty + 8 * r) * D + n0 + tx];
    __syncthreads();
    // 16 x 16 store layout: each lane packs 2 u16 -> uint (2x store width)
    const int tx16 = t & 15, ny = t >> 4;
    #pragma unroll
    for (int r = 0; r < 2; ++r) {
        const int nl = ny + 16 * r;
        union { u16 u[2]; unsigned q; } pk;
        pk.u[0] = f2bf(tile[2 * tx16][nl]);
        pk.u[1] = f2bf(tile[2 * tx16 + 1][nl]);
        ((unsigned*)(o + (size_t)(n0 + nl) * D + k0))[tx16] = pk.q;
    }
}

// ---------------------------------------------------------------------------
extern "C" void kernel_launch(void* const* d_in, const int* in_sizes, int n_in,
                              void* d_out, int out_size, void* d_ws, size_t ws_size,
                              hipStream_t stream)
{
    const int B = 4, S = 2048, D = 1024;
    const int M = B * S;  // 8192

    const float* tokens = (const float*)d_in[0];
    const float* Wq = (const float*)d_in[1];
    const float* bq = (const float*)d_in[2];
    const float* Wk = (const float*)d_in[3];
    const float* bk = (const float*)d_in[4];
    const float* Wv = (const float*)d_in[5];
    const float* bv = (const float*)d_in[6];
    const float* Wo = (const float*)d_in[7];
    const float* bo = (const float*)d_in[8];
    float* out = (float*)d_out;

    // workspace layout (~104 MB)
    char* ws = (char*)d_ws;
    size_t o = 0;
    u16* x_bf = (u16*)(ws + o); o += (size_t)M * D * 2;       // also mixed (PV out)
    u16* wT   = (u16*)(ws + o); o += (size_t)4 * D * D * 2;   // WqT,WkT,WvT,WoT
    u16* q_bf = (u16*)(ws + o); o += (size_t)M * D * 2;
    u16* k_bf = (u16*)(ws + o); o += (size_t)M * D * 2;
    u16* vt   = (u16*)(ws + o); o += (size_t)M * D * 2;       // V transposed [b][d][s]
    u16*   E        = (u16*)(ws + o);   o += (size_t)B * S * S * 2;  // exp(scores) bf16
    float* partials = (float*)(ws + o); o += (size_t)B * S * 16 * 4;
    u16* mixed = x_bf;

    // 1. fused: x = bf16(gelu(tokens))  +  weights -> bf16 transposed
    const int NG = M * D / 8 / 256;   // 4096 gelu blocks
    prep_kernel<<<dim3(NG + 4096), dim3(256), 0, stream>>>(
        (const float4*)tokens, (uint4*)x_bf, Wq, Wk, Wv, Wo, wT, D, NG);

    // 2. Q,K projection: triple-A 256x256, 256 blocks, nz=1 slab map.
    gemm3a<0, 256><<<dim3(2 * D / 256, M / 256, 1), dim3(512), 0, stream>>>(
        x_bf, wT, q_bf, bq, bk,
        D, D, D, D, 0, 0, (long long)M * D, 1.0f, nullptr, 1);

    // 3. V projection via gemm3a EPI4 (single-barrier, slab map): 256 blocks,
    //    V written transposed straight into vt via LDS [128][264] tile.
    gemm3a<4, 128><<<dim3(D / 128, M / 256, 1), dim3(512), 0, stream>>>(
        x_bf, wT + 2 * D * D, vt, bv, nullptr,
        D, D, D, D, 0, 0, 0, 1.0f, nullptr, 1);

    // 4. E[b] = exp(q[b] @ k[b]^T / 32) + partial sums. z folded into gy;
    //    nz=4 gives each XCD one batch-half slab (L2 set ~6 MB).
    gemm3a<1, 256><<<dim3(S / 256, 32, 1), dim3(512), 0, stream>>>(
        q_bf, k_bf, E, nullptr, nullptr,
        D, D, D, S, (long long)S * D, (long long)S * D, (long long)S * S, 0.03125f,
        partials, 4);

    // 5. mixed[b] = (E[b] @ v[b]) * (1/rowsum)   [z folded, nz=4]
    gemm3a<2, 128><<<dim3(D / 128, 32, 1), dim3(512), 0, stream>>>(
        E, vt, mixed, nullptr, nullptr,
        S, S, S, D, (long long)S * S, (long long)D * S, (long long)S * D, 1.0f,
        partials, 4);

    // 6. out = mixed @ Wo + bo + tokens   [nz=1]
    gemm3a<3, 128><<<dim3(D / 128, M / 256, 1), dim3(512), 0, stream>>>(
        mixed, wT + 3 * D * D, out, bo, tokens,
        D, D, D, D, 0, 0, 0, 1.0f, nullptr, 1);
}

// Round 11
// 162.061 us; speedup vs baseline: 1.0096x; 1.0096x over previous
//
#include <hip/hip_runtime.h>
#include <hip/hip_bf16.h>
#include <cstdint>
#include <cstddef>

typedef unsigned short u16;
using frag_ab = __attribute__((ext_vector_type(8))) short;   // 8 bf16 (4 VGPRs)
using f32x4   = __attribute__((ext_vector_type(4))) float;   // 4 fp32 acc

__device__ __forceinline__ u16 f2bf(float x) {
    __hip_bfloat16 h = __float2bfloat16(x);   // RNE
    return *reinterpret_cast<u16*>(&h);
}

// async global->LDS, 16B per lane; LDS dest = wave-uniform base + lane*16 (linear)
__device__ __forceinline__ void gload_lds16(const u16* g, u16* l) {
    __builtin_amdgcn_global_load_lds(
        (const __attribute__((address_space(1))) uint32_t*)g,
        (__attribute__((address_space(3)))       uint32_t*)l,
        16, 0, 0);
}

#define WAITV4() do { asm volatile("s_waitcnt vmcnt(4)" ::: "memory"); \
                      __builtin_amdgcn_sched_barrier(0); } while (0)
#define WAITV0() do { asm volatile("s_waitcnt vmcnt(0)" ::: "memory"); \
                      __builtin_amdgcn_sched_barrier(0); } while (0)
#define BAR()    do { asm volatile("" ::: "memory"); __builtin_amdgcn_s_barrier(); \
                      __builtin_amdgcn_sched_barrier(0); } while (0)
#define LGKMC(N) do { asm volatile("s_waitcnt lgkmcnt(" #N ")" ::: "memory"); \
                      __builtin_amdgcn_sched_barrier(0); } while (0)
#define LGKM0()  LGKMC(0)

// ===========================================================================
// KERNEL gemm3a: 256xBN_ NT bf16 GEMM, TRIPLE-BUFFERED A + double-buffered B,
// 512 thr / 8 waves (4Mx2N).
// R9-proven SINGLE-BARRIER K-TILE: 1 s_barrier + 1 vmcnt(4) + 2 lgkm waits
// per tile. Hazard proof: every wave's frag reads of buffers {ab, bb}
// complete (own LGKM0) BEFORE its BAR; all writes to those buffers (STB@t+1,
// STA@t+1) issue AFTER that same BAR. vmcnt ledger: 12 outstanding at WAITV4
// -> drains A(t+1)+B(t+1), leaves A(t+2).
// L2-footprint-aware XCD tile map (R7-proven): 256-block grids (8,32),
// z folded into gy; XCD c: z=c%nz, compact 4-m-panel slab.
// EPI: 0 = bf16 + bias, plane routed col>>10 (Q/K planes at stride sC)
//      1 = E = exp(s*alpha) bf16 + per-(row,128col-chunk) partial sums
//      2 = bf16 scaled by 1/rowsum(partials) computed in-kernel
//      3 = f32 + bias + residual
// ===========================================================================
template<int EPI, int BN_>
__global__ __launch_bounds__(512, 2)
void gemm3a(const u16* __restrict__ A, const u16* __restrict__ Bt,
            void* __restrict__ C0,
            const float* __restrict__ b0, const float* __restrict__ resid,
            int K, int lda, int ldb, int ldc,
            long long sA, long long sB, long long sC, float alpha,
            float* __restrict__ partials, int nz)
{
    constexpr int NFQ  = BN_ / 64;            // 16-col frags per NQ quadrant
    constexpr int WN   = BN_ / 2;             // per-wave N
    constexpr int BBUF = BN_ * 64;            // u16 per B buffer
    // A: 3 x 16384 u16 at 0; B: 2 x BBUF u16 at 49152.
    __shared__ __align__(16) u16 lds[49152 + 2 * BBUF];

    // --- L2-footprint-aware XCD tile map (256 blocks exactly) ---
    const int gx  = gridDim.x;                       // n-panels (8)
    const int gid = blockIdx.x + gx * blockIdx.y;    // 0..255
    const int c   = gid & 7;                         // XCD (hw: linear%8)
    const int idx = gid >> 3;                        // 0..31 within XCD
    const int z   = c % nz;
    const int sub = c / nz;                          // 0 .. 8/nz-1
    const int W   = gridDim.y >> 3;                  // m-panels per XCD slab (4)
    const int mp  = sub * W + idx % W;               // m-panel
    const int np  = idx / W;                         // n-panel (0..7)
    const int m0  = mp * 256;
    const int n0  = np * BN_;

    A  += (long long)z * sA;
    Bt += (long long)z * sB;

    const int t    = threadIdx.x;
    const int lane = t & 63;
    const int wave = t >> 6;
    const int wm   = wave >> 1;       // 0..3  (64 rows each)
    const int wn   = wave & 1;        // 0..1  (WN cols each)

    const int r0  = t >> 3;
    const int ssw = (t & 7) ^ (r0 & 7);
    const u16* gsA_0 = A  + (size_t)(m0 +       r0) * lda + ssw * 8;
    const u16* gsA_1 = A  + (size_t)(m0 +  64 + r0) * lda + ssw * 8;
    const u16* gsA_2 = A  + (size_t)(m0 + 128 + r0) * lda + ssw * 8;
    const u16* gsA_3 = A  + (size_t)(m0 + 192 + r0) * lda + ssw * 8;
    const u16* gsB_0 = Bt + (size_t)(n0 +       r0) * ldb + ssw * 8;
    const u16* gsB_1 = Bt + (size_t)(n0 +  64 + r0) * ldb + ssw * 8;
    const u16* gsB_2 = (BN_ == 256) ? Bt + (size_t)(n0 + 128 + r0) * ldb + ssw * 8 : gsB_0;
    const u16* gsB_3 = (BN_ == 256) ? Bt + (size_t)(n0 + 192 + r0) * ldb + ssw * 8 : gsB_1;

#define STA(BUF, H, KT) do {                                                   \
    gload_lds16(((H) ? gsA_2 : gsA_0) + (size_t)(KT) * 64,                     \
                lds + (BUF) * 16384 + (H) * 8192 + t * 8);                     \
    gload_lds16(((H) ? gsA_3 : gsA_1) + (size_t)(KT) * 64,                     \
                lds + (BUF) * 16384 + (H) * 8192 + 4096 + t * 8);              \
} while (0)
#define STB(BUF, H, KT) do {                                                   \
    gload_lds16(((H) ? gsB_2 : gsB_0) + (size_t)(KT) * 64,                     \
                lds + 49152 + (BUF) * BBUF + (H) * 8192 + t * 8);              \
    gload_lds16(((H) ? gsB_3 : gsB_1) + (size_t)(KT) * 64,                     \
                lds + 49152 + (BUF) * BBUF + (H) * 8192 + 4096 + t * 8);       \
} while (0)

    const int ar   = lane & 15;
    const int ko   = lane >> 4;
    const int aoff = (wm * 64 + ar) * 64;
    const int boff = 49152 + (wn * WN + ar) * 64;   // includes B-region base
    const int as0  = ((0 + ko) ^ (ar & 7)) * 8;
    const int as1  = ((4 + ko) ^ (ar & 7)) * 8;

    frag_ab aregA[2][2];              // MQ0 fragments (fixed role)
    frag_ab aregB[2][2];              // MQ1 fragments (fixed role)
    frag_ab breg[2][NFQ][2];          // NQ0 / NQ1, persistent per tile
    f32x4   acc[4][2 * NFQ] = {};

#define RDA3(DST, AB, MQ) do { _Pragma("unroll") for (int mf = 0; mf < 2; ++mf) { \
    DST[mf][0] = *(const frag_ab*)(lds + (AB) + aoff + ((MQ)*2+mf)*1024 + as0); \
    DST[mf][1] = *(const frag_ab*)(lds + (AB) + aoff + ((MQ)*2+mf)*1024 + as1); } } while (0)

#define RDB3(BO, NQ) do { _Pragma("unroll") for (int jf = 0; jf < NFQ; ++jf) { \
    breg[NQ][jf][0] = *(const frag_ab*)(lds + (BO) + boff + ((NQ)*NFQ+jf)*1024 + as0); \
    breg[NQ][jf][1] = *(const frag_ab*)(lds + (BO) + boff + ((NQ)*NFQ+jf)*1024 + as1); } } while (0)

#define MMAQ3(ASET, MQ, NQ) do { __builtin_amdgcn_s_setprio(1);                \
    _Pragma("unroll") for (int mf = 0; mf < 2; ++mf)                           \
    _Pragma("unroll") for (int jf = 0; jf < NFQ; ++jf) {                       \
        acc[(MQ)*2+mf][(NQ)*NFQ+jf] = __builtin_amdgcn_mfma_f32_16x16x32_bf16( \
            ASET[mf][0], breg[NQ][jf][0], acc[(MQ)*2+mf][(NQ)*NFQ+jf], 0,0,0); \
        acc[(MQ)*2+mf][(NQ)*NFQ+jf] = __builtin_amdgcn_mfma_f32_16x16x32_bf16( \
            ASET[mf][1], breg[NQ][jf][1], acc[(MQ)*2+mf][(NQ)*NFQ+jf], 0,0,0); \
    } __builtin_amdgcn_s_setprio(0); } while (0)

    const int nk = K / 64;
    // prologue: A(0), B(0), A(1); WAITV4 drains A(0)+B(0), leaves A(1) flying
    STA(0, 0, 0); STA(0, 1, 0);
    STB(0, 0, 0);
    if constexpr (BN_ == 256) STB(0, 1, 0);
    STA(1, 0, 1); STA(1, 1, 1);
    WAITV4();
    BAR();
    // tile0 MQ0 frags (completion covered by first tile's LGKMC)
    RDA3(aregA, 0, 0);

    int ab = 0, bb = 0;
    for (int tt = 0; tt < nk; ++tt) {
        const int abn = (ab + 1 >= 3) ? 0 : ab + 1;        // (ab+1)%3
        const int ab2 = (ab + 2 >= 3) ? ab - 1 : ab + 2;   // (ab+2)%3
        const int bb1 = bb ^ 1;
        const int tB  = (tt + 1 < nk) ? tt + 1 : nk - 1;   // clamped: benign
        const int tA  = (tt + 2 < nk) ? tt + 2 : nk - 1;   // clamped: benign
        const int AB  = ab * 16384, BB = bb * BBUF;
        const int ABn = abn * 16384;
        // --- single-phase tile: reads + B-stage, 2 MFMA quads, A-stage,
        //     drain, ONE barrier, prefetch, 2 MFMA quads ---
        RDA3(aregB, AB, 1);
        RDB3(BB, 0);
        RDB3(BB, 1);                   // breg1 last-issued: LGKMC leaves it
        STB(bb1, 0, tB);
        if constexpr (BN_ == 256) STB(bb1, 1, tB);
        if constexpr (BN_ == 256) { LGKMC(8); } else { LGKMC(4); }
        MMAQ3(aregA, 0, 0);
        LGKM0();
        MMAQ3(aregA, 0, 1);
        STA(ab2, 0, tA);
        STA(ab2, 1, tA);
        MMAQ3(aregB, 1, 0);            // overlaps the WAITV4 drain below
        WAITV4();
        BAR();
        RDA3(aregA, ABn, 0);           // next tile MQ0 (A(t+1) proven in LDS)
        MMAQ3(aregB, 1, 1);
        ab = abn;
        bb = bb1;
    }

    const int cr = (lane >> 4) * 4;
    const int cc = lane & 15;

    // EPI2: fold invl in-kernel. Drain prefetches, reuse LDS for 256 floats.
    float* fl = (float*)lds;
    if constexpr (EPI == 2) {
        WAITV0();
        BAR();
        if (t < 256) {
            const float* p = partials + ((size_t)z * 2048 + m0 + t) * 16;
            float s = 0.0f;
            #pragma unroll
            for (int i = 0; i < 16; ++i) s += p[i];
            fl[t] = 1.0f / s;
        }
        BAR();
    }

    float rs[4][4];
    if constexpr (EPI == 1) {
        #pragma unroll
        for (int mi = 0; mi < 4; ++mi)
            #pragma unroll
            for (int r = 0; r < 4; ++r) rs[mi][r] = 0.0f;
    }

    #pragma unroll
    for (int mi = 0; mi < 4; ++mi) {
        const int rowb = m0 + wm * 64 + mi * 16 + cr;
        const int rloc = wm * 64 + mi * 16 + cr;
        #pragma unroll
        for (int gj = 0; gj < 2 * NFQ; ++gj) {
            const int col = n0 + wn * WN + gj * 16 + cc;
            if constexpr (EPI == 0) {
                // plane-routed bf16 + bias (Q / K planes at stride sC)
                const int plane = col >> 10;
                const int cl    = col & 1023;
                const float bvv = ((plane == 0) ? b0 : resid)[cl];
                u16* Cw = (u16*)C0 + (size_t)plane * sC;
                #pragma unroll
                for (int r = 0; r < 4; ++r)
                    Cw[(size_t)(rowb + r) * ldc + cl] = f2bf(acc[mi][gj][r] + bvv);
            } else {
                const float bvv = (EPI == 3) ? b0[col] : 0.0f;
                #pragma unroll
                for (int r = 0; r < 4; ++r) {
                    const size_t row = (size_t)(rowb + r);
                    float v = acc[mi][gj][r];
                    if (EPI == 1) { v = __expf(v * alpha); rs[mi][r] += v; }
                    if (EPI == 2) v *= fl[rloc + r];
                    v += bvv;
                    if (EPI == 3) {
                        v += resid[row * ldc + col];
                        ((float*)C0)[(size_t)z * sC + row * ldc + col] = v;
                    } else {
                        ((u16*)C0)[(size_t)z * sC + row * ldc + col] = f2bf(v);
                    }
                }
            }
        }
    }

    if constexpr (EPI == 1) {
        #pragma unroll
        for (int mi = 0; mi < 4; ++mi)
            #pragma unroll
            for (int r = 0; r < 4; ++r) {
                float s = rs[mi][r];
                s += __shfl_xor(s, 1); s += __shfl_xor(s, 2);
                s += __shfl_xor(s, 4); s += __shfl_xor(s, 8);
                rs[mi][r] = s;
            }
        if (cc == 0) {
            const int chunk = (n0 >> 7) + wn;   // 128-col chunks (BN256), 16/row
            #pragma unroll
            for (int mi = 0; mi < 4; ++mi) {
                const int rowb = m0 + wm * 64 + mi * 16 + cr;
                #pragma unroll
                for (int r = 0; r < 4; ++r)
                    partials[((size_t)z * 2048 + rowb + r) * 16 + chunk] = rs[mi][r];
            }
        }
    }
#undef STA
#undef STB
#undef RDA3
#undef RDB3
#undef MMAQ3
}

// ===========================================================================
// KERNEL V (R17-proven core): 8-phase 128x128 NT bf16 GEMM, 256 thr / 4
// waves, 64KB LDS -> 2 blocks/CU. V-projection only; epilogue writes V
// TRANSPOSED to vt[b][d][s] via LDS (packed 8B ds_writes).
// R11: restored from R9 (measured-best); R10's EPI4 fold regressed +1.5us.
// ===========================================================================
__global__ __launch_bounds__(256, 2)
void gemm128_v(const u16* __restrict__ A, const u16* __restrict__ Bt,
               u16* __restrict__ VT, const float* __restrict__ bv,
               int K, int lda, int ldb)
{
    constexpr int BUFSTR = 16384;              // u16 per buffer (A 16KB + B 16KB)
    __shared__ __align__(16) u16 lds[2 * BUFSTR];

    const int gx  = gridDim.x;
    const int nwg = gx * gridDim.y;
    const int cpx = nwg >> 3;
    int lin = blockIdx.x + gx * blockIdx.y;
    lin = (lin & 7) * cpx + (lin >> 3);
    const int m0 = (lin / gx) * 128;
    const int n0 = (lin % gx) * 128;

    const int t    = threadIdx.x;
    const int lane = t & 63;
    const int wave = t >> 6;
    const int wm   = wave >> 1;
    const int wn   = wave & 1;

    const int r0  = t >> 3;
    const int ssw = (t & 7) ^ (r0 & 7);
    const u16* gsA0_0 = A  + (size_t)(m0 +       r0) * lda + ssw * 8;
    const u16* gsA0_1 = A  + (size_t)(m0 +  32 + r0) * lda + ssw * 8;
    const u16* gsA1_0 = A  + (size_t)(m0 +  64 + r0) * lda + ssw * 8;
    const u16* gsA1_1 = A  + (size_t)(m0 +  96 + r0) * lda + ssw * 8;
    const u16* gsB0_0 = Bt + (size_t)(n0 +       r0) * ldb + ssw * 8;
    const u16* gsB0_1 = Bt + (size_t)(n0 +  32 + r0) * ldb + ssw * 8;
    const u16* gsB1_0 = Bt + (size_t)(n0 +  64 + r0) * ldb + ssw * 8;
    const u16* gsB1_1 = Bt + (size_t)(n0 +  96 + r0) * ldb + ssw * 8;

#define OPO_A 0
#define OPO_B 8192
#define STAGE(BI, OP, H, KT) do {                                              \
    gload_lds16(gs##OP##H##_0 + (size_t)(KT) * 64,                             \
                lds + (BI) * BUFSTR + OPO_##OP + (H) * 4096 + t * 8);          \
    gload_lds16(gs##OP##H##_1 + (size_t)(KT) * 64,                             \
                lds + (BI) * BUFSTR + OPO_##OP + (H) * 4096 + 2048 + t * 8);   \
} while (0)

    const int ar   = lane & 15;
    const int ko   = lane >> 4;
    const int aoff = (wm * 64 + ar) * 64;
    const int boff = OPO_B + (wn * 64 + ar) * 64;
    const int as0  = ((0 + ko) ^ (ar & 7)) * 8;
    const int as1  = ((4 + ko) ^ (ar & 7)) * 8;

    frag_ab areg[2][2];
    frag_ab breg[2][2][2];
    f32x4   acc[4][4] = {};

#define RDA(BI, MQ) do { _Pragma("unroll") for (int mf = 0; mf < 2; ++mf) {    \
    areg[mf][0] = *(const frag_ab*)(lds + (BI)*BUFSTR + aoff + ((MQ)*2+mf)*1024 + as0); \
    areg[mf][1] = *(const frag_ab*)(lds + (BI)*BUFSTR + aoff + ((MQ)*2+mf)*1024 + as1); } } while (0)

#define RDB(BI, NQ) do { _Pragma("unroll") for (int jf = 0; jf < 2; ++jf) {    \
    breg[NQ][jf][0] = *(const frag_ab*)(lds + (BI)*BUFSTR + boff + ((NQ)*2+jf)*1024 + as0); \
    breg[NQ][jf][1] = *(const frag_ab*)(lds + (BI)*BUFSTR + boff + ((NQ)*2+jf)*1024 + as1); } } while (0)

#define MMAQ(MQ, NQ) do { __builtin_amdgcn_s_setprio(1);                       \
    _Pragma("unroll") for (int mf = 0; mf < 2; ++mf)                           \
    _Pragma("unroll") for (int jf = 0; jf < 2; ++jf) {                         \
        acc[(MQ)*2+mf][(NQ)*2+jf] = __builtin_amdgcn_mfma_f32_16x16x32_bf16(   \
            areg[mf][0], breg[NQ][jf][0], acc[(MQ)*2+mf][(NQ)*2+jf], 0,0,0);   \
        acc[(MQ)*2+mf][(NQ)*2+jf] = __builtin_amdgcn_mfma_f32_16x16x32_bf16(   \
            areg[mf][1], breg[NQ][jf][1], acc[(MQ)*2+mf][(NQ)*2+jf], 0,0,0);   \
    } __builtin_amdgcn_s_setprio(0); } while (0)

    const int nk = K / 64;
    STAGE(0, A, 0, 0); STAGE(0, A, 1, 0); STAGE(0, B, 0, 0); STAGE(0, B, 1, 0);
    STAGE(1, B, 0, 1); STAGE(1, A, 0, 1);
    WAITV4();
    BAR();

    const int nIter = nk >> 1;
    for (int it = 0; it < nIter; ++it) {
        const int O  = 2 * it + 1;
        const int E2 = (2 * it + 2 < nk) ? 2 * it + 2 : nk - 1;
        const int O2 = (2 * it + 3 < nk) ? 2 * it + 3 : nk - 1;

        RDA(0, 0); RDB(0, 0); STAGE(1, A, 1, O);  BAR(); LGKM0(); MMAQ(0, 0);
        RDB(0, 1);            STAGE(1, B, 1, O);  BAR(); LGKM0(); MMAQ(0, 1);
        RDA(0, 1);            STAGE(0, B, 0, E2); BAR(); LGKM0(); MMAQ(1, 0);
        STAGE(0, A, 0, E2);   WAITV4();           BAR();          MMAQ(1, 1);
        RDA(1, 0); RDB(1, 0); STAGE(0, A, 1, E2); BAR(); LGKM0(); MMAQ(0, 0);
        RDB(1, 1);            STAGE(0, B, 1, E2); BAR(); LGKM0(); MMAQ(0, 1);
        RDA(1, 1);            STAGE(1, B, 0, O2); BAR(); LGKM0(); MMAQ(1, 0);
        STAGE(1, A, 0, O2);   WAITV4();           BAR();          MMAQ(1, 1);
    }

    const int cr = (lane >> 4) * 4;
    const int cc = lane & 15;

    // ---- write V transposed to vt[b][d][s] via LDS ----
    WAITV0();   // drain pending prefetch gload_lds before reusing LDS
    BAR();
    constexpr int TP = 136;              // u16 row stride (272B; 8B/16B aligned)
    u16* T = lds;
    #pragma unroll
    for (int mi = 0; mi < 4; ++mi) {
        const int rloc = wm * 64 + mi * 16 + cr;
        #pragma unroll
        for (int gj = 0; gj < 4; ++gj) {
            const int cl = wn * 64 + gj * 16 + cc;
            const float bvv = bv[n0 + cl];
            union { u16 u[4]; uint2 q; } pk;
            #pragma unroll
            for (int r = 0; r < 4; ++r) pk.u[r] = f2bf(acc[mi][gj][r] + bvv);
            *(uint2*)&T[cl * TP + rloc] = pk.q;   // 8B-aligned packed write
        }
    }
    BAR();
    const int bb   = m0 >> 11;           // batch
    const int s0   = m0 & 2047;          // seq offset within batch
    const int d    = t >> 1;             // 0..127 local feature row
    const int half = t & 1;
    const u16* src = T + d * TP + half * 64;
    u16* dg = VT + (size_t)bb * 1024 * 2048 + (size_t)(n0 + d) * 2048 + s0 + half * 64;
    #pragma unroll
    for (int j = 0; j < 8; ++j)
        ((uint4*)dg)[j] = ((const uint4*)src)[j];
#undef STAGE
#undef RDA
#undef RDB
#undef MMAQ
#undef OPO_A
#undef OPO_B
}

// ---------------------------------------------------------------------------
// Fused prep: blocks [0, NG)   : x = bf16(gelu_exact(tokens)), 8 f32/thread
//             blocks [NG, NG+4096): WT[z][n][k] = bf16(W_z[k][n]), 32x32 tiles
//             (packed uint stores)
// ---------------------------------------------------------------------------
__global__ __launch_bounds__(256)
void prep_kernel(const float4* __restrict__ in, uint4* __restrict__ outp,
                 const float* __restrict__ W0, const float* __restrict__ W1,
                 const float* __restrict__ W2, const float* __restrict__ W3,
                 u16* __restrict__ WT, int D, int NG)
{
    __shared__ float tile[32][33];
    const int b = blockIdx.x;
    const int t = threadIdx.x;
    if (b < NG) {
        const int i = (b * 256 + t) * 2;          // float4 index, 2 consecutive
        float4 x0 = in[i], x1 = in[i + 1];
        auto g = [](float v) { return 0.5f * v * (1.0f + erff(v * 0.70710678118654752f)); };
        union { u16 u[8]; uint4 q; } pk;
        pk.u[0] = f2bf(g(x0.x)); pk.u[1] = f2bf(g(x0.y));
        pk.u[2] = f2bf(g(x0.z)); pk.u[3] = f2bf(g(x0.w));
        pk.u[4] = f2bf(g(x1.x)); pk.u[5] = f2bf(g(x1.y));
        pk.u[6] = f2bf(g(x1.z)); pk.u[7] = f2bf(g(x1.w));
        outp[b * 256 + t] = pk.q;
        return;
    }
    const int j   = b - NG;                 // 0..4095
    const int z   = j >> 10;
    const int rem = j & 1023;
    const int n0  = (rem & 31) * 32;
    const int k0  = (rem >> 5) * 32;
    const float* W = (z == 0) ? W0 : (z == 1) ? W1 : (z == 2) ? W2 : W3;
    u16* o = WT + (size_t)z * D * D;
    const int tx = t & 31, ty = t >> 5;     // 32 x 8 load layout
    #pragma unroll
    for (int r = 0; r < 4; ++r)
        tile[ty + 8 * r][tx] = W[(size_t)(k0 + ty + 8 * r) * D + n0 + tx];
    __syncthreads();
    // 16 x 16 store layout: each lane packs 2 u16 -> uint (2x store width)
    const int tx16 = t & 15, ny = t >> 4;
    #pragma unroll
    for (int r = 0; r < 2; ++r) {
        const int nl = ny + 16 * r;
        union { u16 u[2]; unsigned q; } pk;
        pk.u[0] = f2bf(tile[2 * tx16][nl]);
        pk.u[1] = f2bf(tile[2 * tx16 + 1][nl]);
        ((unsigned*)(o + (size_t)(n0 + nl) * D + k0))[tx16] = pk.q;
    }
}

// ---------------------------------------------------------------------------
extern "C" void kernel_launch(void* const* d_in, const int* in_sizes, int n_in,
                              void* d_out, int out_size, void* d_ws, size_t ws_size,
                              hipStream_t stream)
{
    const int B = 4, S = 2048, D = 1024;
    const int M = B * S;  // 8192

    const float* tokens = (const float*)d_in[0];
    const float* Wq = (const float*)d_in[1];
    const float* bq = (const float*)d_in[2];
    const float* Wk = (const float*)d_in[3];
    const float* bk = (const float*)d_in[4];
    const float* Wv = (const float*)d_in[5];
    const float* bv = (const float*)d_in[6];
    const float* Wo = (const float*)d_in[7];
    const float* bo = (const float*)d_in[8];
    float* out = (float*)d_out;

    // workspace layout (~104 MB)
    char* ws = (char*)d_ws;
    size_t o = 0;
    u16* x_bf = (u16*)(ws + o); o += (size_t)M * D * 2;       // also mixed (PV out)
    u16* wT   = (u16*)(ws + o); o += (size_t)4 * D * D * 2;   // WqT,WkT,WvT,WoT
    u16* q_bf = (u16*)(ws + o); o += (size_t)M * D * 2;
    u16* k_bf = (u16*)(ws + o); o += (size_t)M * D * 2;
    u16* vt   = (u16*)(ws + o); o += (size_t)M * D * 2;       // V transposed [b][d][s]
    u16*   E        = (u16*)(ws + o);   o += (size_t)B * S * S * 2;  // exp(scores) bf16
    float* partials = (float*)(ws + o); o += (size_t)B * S * 16 * 4;
    u16* mixed = x_bf;

    // 1. fused: x = bf16(gelu(tokens))  +  weights -> bf16 transposed
    const int NG = M * D / 8 / 256;   // 4096 gelu blocks
    prep_kernel<<<dim3(NG + 4096), dim3(256), 0, stream>>>(
        (const float4*)tokens, (uint4*)x_bf, Wq, Wk, Wv, Wo, wT, D, NG);

    // 2. Q,K projection: triple-A 256x256, 256 blocks, nz=1 slab map.
    gemm3a<0, 256><<<dim3(2 * D / 256, M / 256, 1), dim3(512), 0, stream>>>(
        x_bf, wT, q_bf, bq, bk,
        D, D, D, D, 0, 0, (long long)M * D, 1.0f, nullptr, 1);

    // 3. V projection via 128^2/2-blocks-per-CU kernel; V written transposed
    //    straight into vt (packed-8B LDS transpose epilogue).
    gemm128_v<<<dim3(D / 128, M / 128, 1), dim3(256), 0, stream>>>(
        x_bf, wT + 2 * D * D, vt, bv, D, D, D);

    // 4. E[b] = exp(q[b] @ k[b]^T / 32) + partial sums. z folded into gy;
    //    nz=4 gives each XCD one batch-half slab (L2 set ~6 MB).
    gemm3a<1, 256><<<dim3(S / 256, 32, 1), dim3(512), 0, stream>>>(
        q_bf, k_bf, E, nullptr, nullptr,
        D, D, D, S, (long long)S * D, (long long)S * D, (long long)S * S, 0.03125f,
        partials, 4);

    // 5. mixed[b] = (E[b] @ v[b]) * (1/rowsum)   [z folded, nz=4]
    gemm3a<2, 128><<<dim3(D / 128, 32, 1), dim3(512), 0, stream>>>(
        E, vt, mixed, nullptr, nullptr,
        S, S, S, D, (long long)S * S, (long long)D * S, (long long)S * D, 1.0f,
        partials, 4);

    // 6. out = mixed @ Wo + bo + tokens   [nz=1]
    gemm3a<3, 128><<<dim3(D / 128, M / 256, 1), dim3(512), 0, stream>>>(
        mixed, wT + 3 * D * D, out, bo, tokens,
        D, D, D, D, 0, 0, 0, 1.0f, nullptr, 1);
}